// Round 1
// baseline (1182.955 us; speedup 1.0000x reference)
//
#include <hip/hip_runtime.h>
#include <stdint.h>

// Problem constants (B,S,H,W,L) = (16,2048,512,4,2)
#define Bx   16
#define Sx   2048
#define Hx   512
#define Lx   2
#define PHx  2056            // S + 2W
#define Mx   32768           // B*S

typedef float f32x4  __attribute__((ext_vector_type(4)));
typedef __bf16 bf16x8 __attribute__((ext_vector_type(8)));
typedef unsigned short u16x8 __attribute__((ext_vector_type(8)));

typedef __attribute__((address_space(1))) void gvoid_t;
typedef __attribute__((address_space(3))) void lvoid_t;

__device__ __forceinline__ unsigned short f2bf(float f) {
  uint32_t u = __float_as_uint(f);
  u += 0x7FFFu + ((u >> 16) & 1u);   // round-to-nearest-even
  return (unsigned short)(u >> 16);
}

// ---------------------------------------------------------------------------
// padded[b, r, h]: r<4 -> left_padding, 4..2051 -> inputs, 2052..2055 -> right
// ---------------------------------------------------------------------------
__global__ __launch_bounds__(256) void build_padded_k(
    const float* __restrict__ inp, const float* __restrict__ lp,
    const float* __restrict__ rp, unsigned short* __restrict__ padded) {
  int64_t idx = (int64_t)blockIdx.x * 256 + threadIdx.x;  // < 16*2056*512
  int h = (int)(idx & 511);
  int64_t rowi = idx >> 9;                 // b*2056 + r
  int r = (int)(rowi % 2056);
  int b = (int)(rowi / 2056);
  float v;
  if (r < 4)          v = lp[r * 512 + h];
  else if (r < 2052)  v = inp[((int64_t)b * 2048 + (r - 4)) * 512 + h];
  else                v = rp[(r - 2052) * 512 + h];
  padded[idx] = f2bf(v);
}

// ---------------------------------------------------------------------------
// Convert + transpose all weights to bf16 [N][K] (write-coalesced gather).
// Layout: [0,2M): Wl,Wr ([2048][512] -> [512][2048]); then 8 x [512][512]
// matrices: (lw1,l0),(lw1,l1),(lw2,l0),(lw2,l1),(rw1,..),(rw2,..)
// ---------------------------------------------------------------------------
__global__ __launch_bounds__(256) void prep_weights_k(
    const float* __restrict__ Wl, const float* __restrict__ Wr,
    const float* __restrict__ lw1, const float* __restrict__ lw2,
    const float* __restrict__ rw1, const float* __restrict__ rw2,
    unsigned short* __restrict__ Wlt, unsigned short* __restrict__ Wrt,
    unsigned short* __restrict__ lw1t, unsigned short* __restrict__ lw2t,
    unsigned short* __restrict__ rw1t, unsigned short* __restrict__ rw2t) {
  int idx = blockIdx.x * 256 + threadIdx.x;   // < 4,194,304
  if (idx < 2097152) {
    int j = idx & 1048575;
    const float* src = (idx < 1048576) ? Wl : Wr;
    unsigned short* dst = (idx < 1048576) ? Wlt : Wrt;
    int n = j >> 11, k = j & 2047;
    dst[j] = f2bf(src[(int64_t)k * 512 + n]);
  } else {
    int j = idx - 2097152;
    int mat = j >> 18;                  // 0..7
    int e = j & 262143;
    int arr = mat >> 1, layer = mat & 1;
    const float* srcs[4] = {lw1, lw2, rw1, rw2};
    unsigned short* dsts[4] = {lw1t, lw2t, rw1t, rw2t};
    const float* src = srcs[arr] + (int64_t)layer * 262144;
    unsigned short* dst = dsts[arr] + (int64_t)layer * 262144;
    int n = e >> 9, k = e & 511;
    dst[e] = f2bf(src[k * 512 + n]);
  }
}

// ---------------------------------------------------------------------------
// LayerNorm: one wave per row of 512 fp32 (read from out1 with stride 1024),
// write bf16 xhat [M][512].
// ---------------------------------------------------------------------------
__global__ __launch_bounds__(256) void ln_k(
    const float* __restrict__ x, int x_off,
    const float* __restrict__ g, const float* __restrict__ beta,
    unsigned short* __restrict__ xhat) {
  int row = blockIdx.x * 4 + (threadIdx.x >> 6);
  int lane = threadIdx.x & 63;
  const float4* xr = (const float4*)(x + (int64_t)row * 1024 + x_off);
  float4 u = xr[lane * 2], w = xr[lane * 2 + 1];
  float xs[8] = {u.x, u.y, u.z, u.w, w.x, w.y, w.z, w.w};
  float sum = 0.f, ss = 0.f;
#pragma unroll
  for (int t = 0; t < 8; t++) { sum += xs[t]; ss += xs[t] * xs[t]; }
#pragma unroll
  for (int o = 32; o > 0; o >>= 1) {
    sum += __shfl_xor(sum, o);
    ss  += __shfl_xor(ss, o);
  }
  float mean = sum * (1.0f / 512.0f);
  float var  = ss * (1.0f / 512.0f) - mean * mean;
  float rstd = rsqrtf(var + 1e-5f);
  const float4* g4 = (const float4*)g;
  const float4* b4 = (const float4*)beta;
  float4 ga = g4[lane * 2], gb = g4[lane * 2 + 1];
  float4 ba = b4[lane * 2], bb = b4[lane * 2 + 1];
  float gs[8] = {ga.x, ga.y, ga.z, ga.w, gb.x, gb.y, gb.z, gb.w};
  float bs[8] = {ba.x, ba.y, ba.z, ba.w, bb.x, bb.y, bb.z, bb.w};
  u16x8 val;
#pragma unroll
  for (int t = 0; t < 8; t++) val[t] = f2bf(gs[t] * (xs[t] - mean) * rstd + bs[t]);
  *(u16x8*)(xhat + (int64_t)row * 512 + lane * 8) = val;
}

// ---------------------------------------------------------------------------
// GEMM: C[M,512] = epilogue(A @ Bt^T + bias).  A rows: within a 128-row tile
// (never crosses a batch boundary: 128 | 2048) row stride is 512 elements;
// tile base = A + (m0>>11)*a_bstride + (m0&2047)*512 + a_off.
// Bt is [N][K] bf16 (K contiguous).  128x128 tile, BK=32, 4 waves, 4x4
// mfma_f32_16x16x32_bf16 frags per wave; global_load_lds width-16 staging.
// MODE 0: fp32 out1 at m*1024+c_off+n, relu+bias          (projection)
// MODE 1: bf16 hidden at m*512+n, relu+bias               (FF first GEMM)
// MODE 2: fp32 out1 residual update + bias, and scatter to
//         out0p + s*16384 + b*1024 + c_off + n            (FF second GEMM)
// ---------------------------------------------------------------------------
template <int MODE>
__global__ __launch_bounds__(256) void gemm_k(
    const unsigned short* __restrict__ A, int64_t a_bstride, int a_off, int K,
    const unsigned short* __restrict__ Bt, const float* __restrict__ bias,
    float* __restrict__ C, unsigned short* __restrict__ Cb,
    int c_off, float* __restrict__ out0p) {
  __shared__ unsigned short sA[128 * 32];
  __shared__ unsigned short sB[128 * 32];
  const int tid  = threadIdx.x;
  const int lane = tid & 63;
  const int wave = tid >> 6;
  const int m0 = blockIdx.x * 128;
  const int n0 = blockIdx.y * 128;
  const int wm = (wave >> 1) * 64;
  const int wn = (wave & 1) * 64;
  const int fr = lane >> 4;   // k-group (A/B) / row-group (C)
  const int fc = lane & 15;   // row (A) / col (B, C)

  const unsigned short* Ablk =
      A + (int64_t)(m0 >> 11) * a_bstride + (int64_t)(m0 & 2047) * 512 + a_off;
  const unsigned short* Bblk = Bt + (int64_t)n0 * K;

  f32x4 acc[4][4] = {};

  const int t0 = tid, t1 = tid + 256;
  const int ar0 = t0 >> 2, ac0 = (t0 & 3) * 8;
  const int ar1 = t1 >> 2, ac1 = (t1 & 3) * 8;

  for (int k0 = 0; k0 < K; k0 += 32) {
    __builtin_amdgcn_global_load_lds(
        (gvoid_t*)(Ablk + (int64_t)ar0 * 512 + k0 + ac0),
        (lvoid_t*)(sA + t0 * 8), 16, 0, 0);
    __builtin_amdgcn_global_load_lds(
        (gvoid_t*)(Ablk + (int64_t)ar1 * 512 + k0 + ac1),
        (lvoid_t*)(sA + t1 * 8), 16, 0, 0);
    __builtin_amdgcn_global_load_lds(
        (gvoid_t*)(Bblk + (int64_t)ar0 * K + k0 + ac0),
        (lvoid_t*)(sB + t0 * 8), 16, 0, 0);
    __builtin_amdgcn_global_load_lds(
        (gvoid_t*)(Bblk + (int64_t)ar1 * K + k0 + ac1),
        (lvoid_t*)(sB + t1 * 8), 16, 0, 0);
    __syncthreads();

    bf16x8 af[4], bf[4];
#pragma unroll
    for (int i = 0; i < 4; i++)
      af[i] = *(const bf16x8*)(sA + (wm + i * 16 + fc) * 32 + fr * 8);
#pragma unroll
    for (int j = 0; j < 4; j++)
      bf[j] = *(const bf16x8*)(sB + (wn + j * 16 + fc) * 32 + fr * 8);
#pragma unroll
    for (int i = 0; i < 4; i++)
#pragma unroll
      for (int j = 0; j < 4; j++)
        acc[i][j] = __builtin_amdgcn_mfma_f32_16x16x32_bf16(af[i], bf[j], acc[i][j], 0, 0, 0);
    __syncthreads();
  }

  // epilogue: acc[i][j][r] -> row m0+wm+i*16+fr*4+r, col n0+wn+j*16+fc
  int col[4];
  float bv[4];
#pragma unroll
  for (int j = 0; j < 4; j++) {
    col[j] = n0 + wn + j * 16 + fc;
    bv[j] = bias[col[j]];
  }
  const int b_idx = m0 >> 11;
#pragma unroll
  for (int i = 0; i < 4; i++) {
#pragma unroll
    for (int r = 0; r < 4; r++) {
      const int m = m0 + wm + i * 16 + fr * 4 + r;
      if (MODE == 0) {
        const int64_t base = (int64_t)m * 1024 + c_off;
#pragma unroll
        for (int j = 0; j < 4; j++) {
          float v = acc[i][j][r] + bv[j];
          C[base + col[j]] = v > 0.f ? v : 0.f;
        }
      } else if (MODE == 1) {
        const int64_t base = (int64_t)m * 512;
#pragma unroll
        for (int j = 0; j < 4; j++) {
          float v = acc[i][j][r] + bv[j];
          Cb[base + col[j]] = f2bf(v > 0.f ? v : 0.f);
        }
      } else {
        const int64_t base = (int64_t)m * 1024 + c_off;
        const int s = m & 2047;
        const int64_t obase = (int64_t)s * 16384 + (int64_t)b_idx * 1024 + c_off;
#pragma unroll
        for (int j = 0; j < 4; j++) {
          float v = C[base + col[j]] + acc[i][j][r] + bv[j];
          C[base + col[j]] = v;
          out0p[obase + col[j]] = v;
        }
      }
    }
  }
}

// ---------------------------------------------------------------------------
extern "C" void kernel_launch(void* const* d_in, const int* in_sizes, int n_in,
                              void* d_out, int out_size, void* d_ws, size_t ws_size,
                              hipStream_t stream) {
  const float* inputs = (const float*)d_in[0];
  const float* lp     = (const float*)d_in[1];
  const float* rp     = (const float*)d_in[2];
  const float* Wl     = (const float*)d_in[3];
  const float* bl     = (const float*)d_in[4];
  const float* Wr     = (const float*)d_in[5];
  const float* br     = (const float*)d_in[6];
  const float* lw1    = (const float*)d_in[7];
  const float* lb1    = (const float*)d_in[8];
  const float* lw2    = (const float*)d_in[9];
  const float* lb2    = (const float*)d_in[10];
  const float* lg     = (const float*)d_in[11];
  const float* lbeta  = (const float*)d_in[12];
  const float* rw1    = (const float*)d_in[13];
  const float* rb1    = (const float*)d_in[14];
  const float* rw2    = (const float*)d_in[15];
  const float* rb2    = (const float*)d_in[16];
  const float* rg     = (const float*)d_in[17];
  const float* rbeta  = (const float*)d_in[18];

  float* out0 = (float*)d_out;                              // all_layers [L,S,B,2H]
  float* out1 = out0 + (int64_t)Lx * Sx * Bx * 1024;        // last_layers [B,S,2H] (doubles as lo/ro state)

  char* w = (char*)d_ws;
  auto take = [&](size_t n) { char* p = w; w += (n + 255) & ~(size_t)255; return p; };
  unsigned short* padded = (unsigned short*)take((size_t)Bx * PHx * Hx * 2);
  unsigned short* Wlt    = (unsigned short*)take(2048ull * 512 * 2);
  unsigned short* Wrt    = (unsigned short*)take(2048ull * 512 * 2);
  unsigned short* lw1t   = (unsigned short*)take((size_t)Lx * 512 * 512 * 2);
  unsigned short* lw2t   = (unsigned short*)take((size_t)Lx * 512 * 512 * 2);
  unsigned short* rw1t   = (unsigned short*)take((size_t)Lx * 512 * 512 * 2);
  unsigned short* rw2t   = (unsigned short*)take((size_t)Lx * 512 * 512 * 2);
  unsigned short* xhat   = (unsigned short*)take((size_t)Mx * 512 * 2);
  unsigned short* hidden = (unsigned short*)take((size_t)Mx * 512 * 2);

  build_padded_k<<<65792, 256, 0, stream>>>(inputs, lp, rp, padded);
  prep_weights_k<<<16384, 256, 0, stream>>>(Wl, Wr, lw1, lw2, rw1, rw2,
                                            Wlt, Wrt, lw1t, lw2t, rw1t, rw2t);

  dim3 gg(256, 4);
  // projections: left (cols 0..511), right (cols 512..1023); right window at +5*H
  gemm_k<0><<<gg, 256, 0, stream>>>(padded, (int64_t)PHx * 512, 0, 2048, Wlt, bl,
                                    out1, nullptr, 0, nullptr);
  gemm_k<0><<<gg, 256, 0, stream>>>(padded, (int64_t)PHx * 512, 5 * 512, 2048, Wrt, br,
                                    out1, nullptr, 512, nullptr);

  for (int i = 0; i < Lx; i++) {
    for (int side = 0; side < 2; side++) {
      const float* g  = (side ? rg : lg) + i * 512;
      const float* be = (side ? rbeta : lbeta) + i * 512;
      const float* b1 = (side ? rb1 : lb1) + i * 512;
      const float* b2 = (side ? rb2 : lb2) + i * 512;
      const unsigned short* w1t = (side ? rw1t : lw1t) + (int64_t)i * 262144;
      const unsigned short* w2t = (side ? rw2t : lw2t) + (int64_t)i * 262144;

      ln_k<<<8192, 256, 0, stream>>>(out1, side * 512, g, be, xhat);
      gemm_k<1><<<gg, 256, 0, stream>>>(xhat, (int64_t)2048 * 512, 0, 512, w1t, b1,
                                        nullptr, hidden, 0, nullptr);
      gemm_k<2><<<gg, 256, 0, stream>>>(hidden, (int64_t)2048 * 512, 0, 512, w2t, b2,
                                        out1, nullptr, side * 512,
                                        out0 + (int64_t)i * Sx * Bx * 1024);
    }
  }
}

// Round 2
// 1074.865 us; speedup vs baseline: 1.1006x; 1.1006x over previous
//
#include <hip/hip_runtime.h>
#include <stdint.h>

// Problem constants (B,S,H,W,L) = (16,2048,512,4,2)
#define Bx   16
#define Sx   2048
#define Hx   512
#define Lx   2
#define PHx  2056            // S + 2W
#define Mx   32768           // B*S

typedef float f32x4  __attribute__((ext_vector_type(4)));
typedef __bf16 bf16x8 __attribute__((ext_vector_type(8)));
typedef unsigned short u16x8 __attribute__((ext_vector_type(8)));

typedef __attribute__((address_space(1))) void gvoid_t;
typedef __attribute__((address_space(3))) void lvoid_t;

__device__ __forceinline__ unsigned short f2bf(float f) {
  uint32_t u = __float_as_uint(f);
  u += 0x7FFFu + ((u >> 16) & 1u);   // round-to-nearest-even
  return (unsigned short)(u >> 16);
}

// ---------------------------------------------------------------------------
// padded[b, r, h]: r<4 -> left_padding, 4..2051 -> inputs, 2052..2055 -> right
// 8 elems/thread, vectorized.
// ---------------------------------------------------------------------------
__global__ __launch_bounds__(256) void build_padded_k(
    const float* __restrict__ inp, const float* __restrict__ lp,
    const float* __restrict__ rp, unsigned short* __restrict__ padded) {
  int64_t idx = ((int64_t)blockIdx.x * 256 + threadIdx.x) * 8;  // < 16*2056*512
  int h = (int)(idx & 511);
  int64_t rowi = idx >> 9;                 // b*2056 + r
  int r = (int)(rowi % 2056);
  int b = (int)(rowi / 2056);
  const float* src;
  if (r < 4)          src = lp + r * 512 + h;
  else if (r < 2052)  src = inp + ((int64_t)b * 2048 + (r - 4)) * 512 + h;
  else                src = rp + (r - 2052) * 512 + h;
  float4 u = ((const float4*)src)[0];
  float4 w = ((const float4*)src)[1];
  u16x8 o;
  o[0] = f2bf(u.x); o[1] = f2bf(u.y); o[2] = f2bf(u.z); o[3] = f2bf(u.w);
  o[4] = f2bf(w.x); o[5] = f2bf(w.y); o[6] = f2bf(w.z); o[7] = f2bf(w.w);
  *(u16x8*)(padded + idx) = o;
}

// ---------------------------------------------------------------------------
// Weight prep: bf16 [N][K] transpose via LDS 32x32 tiles.
// blocks [0,2048): Wl,Wr ([2048][512] -> [512][2048]), 1024 tiles each.
// blocks [2048,4096): 8 x [512][512] mats, 256 tiles each.
// ---------------------------------------------------------------------------
__global__ __launch_bounds__(256) void prep_weights_k(
    const float* __restrict__ Wl, const float* __restrict__ Wr,
    const float* __restrict__ lw1, const float* __restrict__ lw2,
    const float* __restrict__ rw1, const float* __restrict__ rw2,
    unsigned short* __restrict__ Wlt, unsigned short* __restrict__ Wrt,
    unsigned short* __restrict__ lw1t, unsigned short* __restrict__ lw2t,
    unsigned short* __restrict__ rw1t, unsigned short* __restrict__ rw2t) {
  __shared__ unsigned short tl[32][36];
  int b = blockIdx.x;
  const float* src; unsigned short* dst; int K, tk, tn;
  if (b < 2048) {
    src = (b < 1024) ? Wl : Wr;
    dst = (b < 1024) ? Wlt : Wrt;
    int t = b & 1023; tk = t >> 4; tn = t & 15; K = 2048;
  } else {
    int b2 = b - 2048;
    int mat = b2 >> 8;  // 0..7: (lw1,0),(lw1,1),(lw2,0),(lw2,1),(rw1,..),(rw2,..)
    const float* srcs[8] = {lw1, lw1 + 262144, lw2, lw2 + 262144,
                            rw1, rw1 + 262144, rw2, rw2 + 262144};
    unsigned short* dsts[8] = {lw1t, lw1t + 262144, lw2t, lw2t + 262144,
                               rw1t, rw1t + 262144, rw2t, rw2t + 262144};
    src = srcs[mat]; dst = dsts[mat];
    int tt = b2 & 255; tk = tt >> 4; tn = tt & 15; K = 512;
  }
  int t = threadIdx.x;
  int rr = t >> 3, c4 = (t & 7) * 4;
  float4 v = *(const float4*)(src + (int64_t)(tk * 32 + rr) * 512 + tn * 32 + c4);
  tl[c4 + 0][rr] = f2bf(v.x);
  tl[c4 + 1][rr] = f2bf(v.y);
  tl[c4 + 2][rr] = f2bf(v.z);
  tl[c4 + 3][rr] = f2bf(v.w);
  __syncthreads();
  int nn = t >> 3, k4 = (t & 7) * 4;
  ushort4 o = {tl[nn][k4], tl[nn][k4 + 1], tl[nn][k4 + 2], tl[nn][k4 + 3]};
  *(ushort4*)(dst + (int64_t)(tn * 32 + nn) * K + tk * 32 + k4) = o;
}

// ---------------------------------------------------------------------------
// GEMM (producer): C[M,512 cols of side z] = epilogue(A @ Bt^T + bias).
// grid (256, 4, 2): z = side. 128x128 tile, BK=32, 4 waves, 4x4 mfma 16x16x32.
// MODE 0: v = relu(acc+bias); C[m*1024 + z*512 + n] = v       (projection)
// MODE 2: v = C[..] + acc + bias; C[..] = v; out0p[s*16384+b*1024+z*512+n] = v
// STATS: per-row (sum, sumsq) of v -> P[(z*4+nb)*M + m][2]  (non-atomic)
// ---------------------------------------------------------------------------
template <int MODE, bool STATS>
__global__ __launch_bounds__(256) void gemm_k(
    const unsigned short* __restrict__ A0, const unsigned short* __restrict__ A1,
    int64_t a_bstride, int a_off_per_z, int K,
    const unsigned short* __restrict__ Bt0, const unsigned short* __restrict__ Bt1,
    const float* __restrict__ bias0, const float* __restrict__ bias1,
    float* __restrict__ C, float* __restrict__ out0p, float* __restrict__ P) {
  __shared__ unsigned short sA[128 * 32];
  __shared__ unsigned short sB[128 * 32];
  __shared__ float sls[128][2][2];
  const int tid  = threadIdx.x;
  const int lane = tid & 63;
  const int wave = tid >> 6;
  const int m0 = blockIdx.x * 128;
  const int n0 = blockIdx.y * 128;
  const int z  = blockIdx.z;
  const int wm = (wave >> 1) * 64;
  const int wn = (wave & 1) * 64;
  const int fr = lane >> 4;
  const int fc = lane & 15;

  const unsigned short* A  = z ? A1 : A0;
  const unsigned short* Bt = z ? Bt1 : Bt0;
  const float* bias = z ? bias1 : bias0;
  const int a_off = z * a_off_per_z;
  const int c_off = z * 512;

  const unsigned short* Ablk =
      A + (int64_t)(m0 >> 11) * a_bstride + (int64_t)(m0 & 2047) * 512 + a_off;
  const unsigned short* Bblk = Bt + (int64_t)n0 * K;

  f32x4 acc[4][4] = {};

  const int t0 = tid, t1 = tid + 256;
  const int ar0 = t0 >> 2, ac0 = (t0 & 3) * 8;
  const int ar1 = t1 >> 2, ac1 = (t1 & 3) * 8;

  for (int k0 = 0; k0 < K; k0 += 32) {
    __builtin_amdgcn_global_load_lds(
        (gvoid_t*)(Ablk + (int64_t)ar0 * 512 + k0 + ac0),
        (lvoid_t*)(sA + t0 * 8), 16, 0, 0);
    __builtin_amdgcn_global_load_lds(
        (gvoid_t*)(Ablk + (int64_t)ar1 * 512 + k0 + ac1),
        (lvoid_t*)(sA + t1 * 8), 16, 0, 0);
    __builtin_amdgcn_global_load_lds(
        (gvoid_t*)(Bblk + (int64_t)ar0 * K + k0 + ac0),
        (lvoid_t*)(sB + t0 * 8), 16, 0, 0);
    __builtin_amdgcn_global_load_lds(
        (gvoid_t*)(Bblk + (int64_t)ar1 * K + k0 + ac1),
        (lvoid_t*)(sB + t1 * 8), 16, 0, 0);
    __syncthreads();

    bf16x8 af[4], bf[4];
#pragma unroll
    for (int i = 0; i < 4; i++)
      af[i] = *(const bf16x8*)(sA + (wm + i * 16 + fc) * 32 + fr * 8);
#pragma unroll
    for (int j = 0; j < 4; j++)
      bf[j] = *(const bf16x8*)(sB + (wn + j * 16 + fc) * 32 + fr * 8);
#pragma unroll
    for (int i = 0; i < 4; i++)
#pragma unroll
      for (int j = 0; j < 4; j++)
        acc[i][j] = __builtin_amdgcn_mfma_f32_16x16x32_bf16(af[i], bf[j], acc[i][j], 0, 0, 0);
    __syncthreads();
  }

  // epilogue: acc[i][j][r] -> row m0+wm+i*16+fr*4+r, col n0+wn+j*16+fc
  int col[4];
  float bv[4];
#pragma unroll
  for (int j = 0; j < 4; j++) {
    col[j] = n0 + wn + j * 16 + fc;
    bv[j] = bias[col[j]];
  }
  const int b_idx = m0 >> 11;
#pragma unroll
  for (int i = 0; i < 4; i++) {
#pragma unroll
    for (int r = 0; r < 4; r++) {
      const int m = m0 + wm + i * 16 + fr * 4 + r;
      const int64_t base = (int64_t)m * 1024 + c_off;
      float vs[4];
      if (MODE == 0) {
#pragma unroll
        for (int j = 0; j < 4; j++) {
          float v = acc[i][j][r] + bv[j];
          v = v > 0.f ? v : 0.f;
          C[base + col[j]] = v;
          vs[j] = v;
        }
      } else {
        const int s = m & 2047;
        const int64_t obase = (int64_t)s * 16384 + (int64_t)b_idx * 1024 + c_off;
#pragma unroll
        for (int j = 0; j < 4; j++) {
          float v = C[base + col[j]] + acc[i][j][r] + bv[j];
          C[base + col[j]] = v;
          out0p[obase + col[j]] = v;
          vs[j] = v;
        }
      }
      if (STATS) {
        float s1 = vs[0] + vs[1] + vs[2] + vs[3];
        float s2 = vs[0] * vs[0] + vs[1] * vs[1] + vs[2] * vs[2] + vs[3] * vs[3];
#pragma unroll
        for (int o = 1; o < 16; o <<= 1) {
          s1 += __shfl_xor(s1, o);
          s2 += __shfl_xor(s2, o);
        }
        if (fc == 0) {
          int li = (wave >> 1) * 64 + i * 16 + fr * 4 + r;
          sls[li][wave & 1][0] = s1;
          sls[li][wave & 1][1] = s2;
        }
      }
    }
  }
  if (STATS) {
    __syncthreads();
    int li = tid >> 1, comp = tid & 1;
    float v = sls[li][0][comp] + sls[li][1][comp];
    P[(((int64_t)z * 4 + blockIdx.y) * Mx + m0 + li) * 2 + comp] = v;
  }
}

// ---------------------------------------------------------------------------
// FF first GEMM with fused LayerNorm on A-load:
// hidden[z][m][n] = relu( LN(state_row_m, side z) @ w1^T + b1 )
// A staged via VGPRs from fp32 state (out1), normalized with stats from P.
// B staged via global_load_lds. K = 512 fixed.
// ---------------------------------------------------------------------------
__global__ __launch_bounds__(256) void gemm_ln_k(
    const float* __restrict__ state, const float* __restrict__ P,
    const float* __restrict__ g0, const float* __restrict__ g1p,
    const float* __restrict__ be0, const float* __restrict__ be1,
    const unsigned short* __restrict__ Bt0, const unsigned short* __restrict__ Bt1,
    const float* __restrict__ bias0, const float* __restrict__ bias1,
    unsigned short* __restrict__ hidden) {
  __shared__ unsigned short sA[128 * 32];
  __shared__ unsigned short sB[128 * 32];
  const int tid  = threadIdx.x;
  const int lane = tid & 63;
  const int wave = tid >> 6;
  const int m0 = blockIdx.x * 128;
  const int n0 = blockIdx.y * 128;
  const int z  = blockIdx.z;
  const int wm = (wave >> 1) * 64;
  const int wn = (wave & 1) * 64;
  const int fr = lane >> 4;
  const int fc = lane & 15;

  const unsigned short* Bt = z ? Bt1 : Bt0;
  const float* bias = z ? bias1 : bias0;
  const float* g    = z ? g1p : g0;
  const float* be   = z ? be1 : be0;
  const int c_off = z * 512;
  const unsigned short* Bblk = Bt + (int64_t)n0 * 512;

  // A-staging mapping: thread -> (row, 16-col half)
  const int row  = tid >> 1;
  const int half = tid & 1;
  const int m = m0 + row;
  const float* srcrow = state + (int64_t)m * 1024 + c_off + half * 16;

  // row stats: combine 4 n-block partials
  float s1 = 0.f, s2 = 0.f;
#pragma unroll
  for (int nb = 0; nb < 4; nb++) {
    s1 += P[(((int64_t)z * 4 + nb) * Mx + m) * 2 + 0];
    s2 += P[(((int64_t)z * 4 + nb) * Mx + m) * 2 + 1];
  }
  const float mean = s1 * (1.0f / 512.0f);
  const float rstd = rsqrtf(s2 * (1.0f / 512.0f) - mean * mean + 1e-5f);

  f32x4 acc[4][4] = {};

  const int t0 = tid, t1 = tid + 256;
  const int br0 = t0 >> 2, bc0 = (t0 & 3) * 8;
  const int br1 = t1 >> 2, bc1 = (t1 & 3) * 8;

  for (int k0 = 0; k0 < 512; k0 += 32) {
    __builtin_amdgcn_global_load_lds(
        (gvoid_t*)(Bblk + (int64_t)br0 * 512 + k0 + bc0),
        (lvoid_t*)(sB + t0 * 8), 16, 0, 0);
    __builtin_amdgcn_global_load_lds(
        (gvoid_t*)(Bblk + (int64_t)br1 * 512 + k0 + bc1),
        (lvoid_t*)(sB + t1 * 8), 16, 0, 0);

    const float* sp = srcrow + k0;
    float xs[16], gs[16], bs[16];
    *(float4*)(xs + 0)  = ((const float4*)sp)[0];
    *(float4*)(xs + 4)  = ((const float4*)sp)[1];
    *(float4*)(xs + 8)  = ((const float4*)sp)[2];
    *(float4*)(xs + 12) = ((const float4*)sp)[3];
    const float* gp = g + k0 + half * 16;
    const float* bp = be + k0 + half * 16;
    *(float4*)(gs + 0)  = ((const float4*)gp)[0];
    *(float4*)(gs + 4)  = ((const float4*)gp)[1];
    *(float4*)(gs + 8)  = ((const float4*)gp)[2];
    *(float4*)(gs + 12) = ((const float4*)gp)[3];
    *(float4*)(bs + 0)  = ((const float4*)bp)[0];
    *(float4*)(bs + 4)  = ((const float4*)bp)[1];
    *(float4*)(bs + 8)  = ((const float4*)bp)[2];
    *(float4*)(bs + 12) = ((const float4*)bp)[3];
    u16x8 o0, o1;
#pragma unroll
    for (int t = 0; t < 8; t++)
      o0[t] = f2bf((xs[t] - mean) * rstd * gs[t] + bs[t]);
#pragma unroll
    for (int t = 0; t < 8; t++)
      o1[t] = f2bf((xs[t + 8] - mean) * rstd * gs[t + 8] + bs[t + 8]);
    *(u16x8*)(sA + row * 32 + half * 16)     = o0;
    *(u16x8*)(sA + row * 32 + half * 16 + 8) = o1;
    __syncthreads();

    bf16x8 af[4], bf[4];
#pragma unroll
    for (int i = 0; i < 4; i++)
      af[i] = *(const bf16x8*)(sA + (wm + i * 16 + fc) * 32 + fr * 8);
#pragma unroll
    for (int j = 0; j < 4; j++)
      bf[j] = *(const bf16x8*)(sB + (wn + j * 16 + fc) * 32 + fr * 8);
#pragma unroll
    for (int i = 0; i < 4; i++)
#pragma unroll
      for (int j = 0; j < 4; j++)
        acc[i][j] = __builtin_amdgcn_mfma_f32_16x16x32_bf16(af[i], bf[j], acc[i][j], 0, 0, 0);
    __syncthreads();
  }

  unsigned short* Cb = hidden + (int64_t)z * Mx * 512;
  int col[4];
  float bv[4];
#pragma unroll
  for (int j = 0; j < 4; j++) {
    col[j] = n0 + wn + j * 16 + fc;
    bv[j] = bias[col[j]];
  }
#pragma unroll
  for (int i = 0; i < 4; i++) {
#pragma unroll
    for (int r = 0; r < 4; r++) {
      const int mm = m0 + wm + i * 16 + fr * 4 + r;
      const int64_t base = (int64_t)mm * 512;
#pragma unroll
      for (int j = 0; j < 4; j++) {
        float v = acc[i][j][r] + bv[j];
        Cb[base + col[j]] = f2bf(v > 0.f ? v : 0.f);
      }
    }
  }
}

// ---------------------------------------------------------------------------
extern "C" void kernel_launch(void* const* d_in, const int* in_sizes, int n_in,
                              void* d_out, int out_size, void* d_ws, size_t ws_size,
                              hipStream_t stream) {
  const float* inputs = (const float*)d_in[0];
  const float* lp     = (const float*)d_in[1];
  const float* rp     = (const float*)d_in[2];
  const float* Wl     = (const float*)d_in[3];
  const float* bl     = (const float*)d_in[4];
  const float* Wr     = (const float*)d_in[5];
  const float* br     = (const float*)d_in[6];
  const float* lw1    = (const float*)d_in[7];
  const float* lb1    = (const float*)d_in[8];
  const float* lw2    = (const float*)d_in[9];
  const float* lb2    = (const float*)d_in[10];
  const float* lg     = (const float*)d_in[11];
  const float* lbeta  = (const float*)d_in[12];
  const float* rw1    = (const float*)d_in[13];
  const float* rb1    = (const float*)d_in[14];
  const float* rw2    = (const float*)d_in[15];
  const float* rb2    = (const float*)d_in[16];
  const float* rg     = (const float*)d_in[17];
  const float* rbeta  = (const float*)d_in[18];

  float* out0 = (float*)d_out;                              // all_layers [L,S,B,2H]
  float* out1 = out0 + (int64_t)Lx * Sx * Bx * 1024;        // last_layers (lo/ro state)

  char* w = (char*)d_ws;
  auto take = [&](size_t n) { char* p = w; w += (n + 255) & ~(size_t)255; return p; };
  unsigned short* padded = (unsigned short*)take((size_t)Bx * PHx * Hx * 2);
  unsigned short* Wlt    = (unsigned short*)take(2048ull * 512 * 2);
  unsigned short* Wrt    = (unsigned short*)take(2048ull * 512 * 2);
  unsigned short* lw1t   = (unsigned short*)take((size_t)Lx * 512 * 512 * 2);
  unsigned short* lw2t   = (unsigned short*)take((size_t)Lx * 512 * 512 * 2);
  unsigned short* rw1t   = (unsigned short*)take((size_t)Lx * 512 * 512 * 2);
  unsigned short* rw2t   = (unsigned short*)take((size_t)Lx * 512 * 512 * 2);
  unsigned short* hidden = (unsigned short*)take((size_t)2 * Mx * 512 * 2);
  float*          Pst    = (float*)take((size_t)2 * 4 * Mx * 2 * 4);

  build_padded_k<<<8224, 256, 0, stream>>>(inputs, lp, rp, padded);
  prep_weights_k<<<4096, 256, 0, stream>>>(Wl, Wr, lw1, lw2, rw1, rw2,
                                           Wlt, Wrt, lw1t, lw2t, rw1t, rw2t);

  dim3 gg(256, 4, 2);
  // projections (z=0 left a_off=0, z=1 right a_off=2560), with LN stats
  gemm_k<0, true><<<gg, 256, 0, stream>>>(
      padded, padded, (int64_t)PHx * 512, 5 * 512, 2048,
      Wlt, Wrt, bl, br, out1, nullptr, Pst);

  for (int i = 0; i < Lx; i++) {
    gemm_ln_k<<<gg, 256, 0, stream>>>(
        out1, Pst, lg + i * 512, rg + i * 512, lbeta + i * 512, rbeta + i * 512,
        lw1t + (int64_t)i * 262144, rw1t + (int64_t)i * 262144,
        lb1 + i * 512, rb1 + i * 512, hidden);
    if (i == 0) {
      gemm_k<2, true><<<gg, 256, 0, stream>>>(
          hidden, hidden + (int64_t)Mx * 512, (int64_t)2048 * 512, 0, 512,
          lw2t, rw2t, lb2, rb2, out1, out0, Pst);
    } else {
      gemm_k<2, false><<<gg, 256, 0, stream>>>(
          hidden, hidden + (int64_t)Mx * 512, (int64_t)2048 * 512, 0, 512,
          lw2t + (int64_t)i * 262144, rw2t + (int64_t)i * 262144,
          lb2 + i * 512, rb2 + i * 512, out1,
          out0 + (int64_t)i * Sx * Bx * 1024, nullptr);
    }
  }
}